// Round 10
// baseline (225.564 us; speedup 1.0000x reference)
//
#include <hip/hip_runtime.h>

// Problem constants (from reference)
#define CC 9605
#define BB 2048
#define LL 8
#define NEGF (-1e30f)
#define NINF (-__builtin_huge_valf())

// d_ws layout (unsigned words):
//   wsu[0] = wl entry count (atomic)
//   wsu[1] = dtype sniff flags (atomic OR)
//   wsu[4 .. 4+2048) = whitelist entries (col<<8 | mask)
//   byte offset 16384: float partials[BB]
#define WS_PARTIALS_OFF 16384

__device__ __forceinline__ unsigned enc_f(float f) {
  unsigned u = __float_as_uint(f);
  return (u & 0x80000000u) ? ~u : (u | 0x80000000u);
}
__device__ __forceinline__ float dec_u(unsigned e) {
  unsigned u = (e & 0x80000000u) ? (e & 0x7fffffffu) : ~e;
  return __uint_as_float(u);
}
__device__ __forceinline__ float sigm(float z) {
  return 1.0f / (1.0f + __expf(-z));
}
// Async global->LDS copy, 16B per lane per call. Side-effecting VMEM op with
// no SSA result: the compiler CANNOT sink it to its use, so all staging
// loads issue back-to-back and stay in flight until the vmcnt(0) that
// __syncthreads emits. This is the one load path hipcc can't de-pipeline.
__device__ __forceinline__ void stage16(const void* g, void* l) {
  __builtin_amdgcn_global_load_lds(
      (const __attribute__((address_space(1))) void*)g,
      (__attribute__((address_space(3))) void*)l, 16, 0, 0);
}

// ---- dtype sniff (word loads): byte signatures over the raw wl buffer ----
//   u8  : byte==1 at offsets %4 != 0        -> flag 1 (and 2)
//   i32 : byte==1 only at offsets %4 == 0   -> flag 2
//   f32 : 0x3f at %4==3, never byte==1      -> flag 8
//   bf16: 0x3f at odd offsets incl %4==1    -> flag 4 (and 8)
__global__ void wl_sniff(const unsigned* __restrict__ wlw,
                         unsigned* __restrict__ wsu) {
  const int nwords = (LL * CC) / 4;  // 76840 % 4 == 0
  const int stride = gridDim.x * blockDim.x;
  unsigned f = 0u;
  for (int j = blockIdx.x * blockDim.x + threadIdx.x; j < nwords; j += stride) {
    unsigned w = wlw[j];
#pragma unroll
    for (int k = 0; k < 4; ++k) {
      unsigned b = (w >> (8 * k)) & 255u;
      if (b == 1u)    { f |= 2u; if (k != 0) f |= 1u; }
      if (b == 0x3fu) { f |= 8u; if (k == 1) f |= 4u; }
    }
  }
#pragma unroll
  for (int off = 32; off >= 1; off >>= 1) f |= __shfl_xor(f, off, 64);
  if ((threadIdx.x & 63) == 0 && f) atomicOr(&wsu[1], f);
}

__global__ void wl_compact(const unsigned char* __restrict__ wl,
                           unsigned* __restrict__ wsu) {
  const int tid = threadIdx.x;
  const int lane = tid & 63;
  const int c = blockIdx.x * 256 + tid;
  const unsigned g = wsu[1];
  const int dt = (g & 1u) ? 0 : (g & 4u) ? 3 : (g & 2u) ? 1 : (g & 8u) ? 2 : 0;
  const int* wl32 = (const int*)wl;
  const float* wlf = (const float*)wl;
  const unsigned short* wlh = (const unsigned short*)wl;
  unsigned m = 0u;
  if (c < CC) {
#pragma unroll
    for (int l = 0; l < LL; ++l) {
      int j = l * CC + c;
      bool on;
      if (dt == 0) on = (wl[j] != 0);
      else if (dt == 1) on = (wl32[j] != 0);
      else if (dt == 2) on = (wlf[j] != 0.0f);
      else on = (wlh[j] != 0);
      if (on) m |= (1u << l);
    }
  }
  unsigned long long bal = __ballot(m != 0u);
  if (bal) {
    unsigned wcnt = (unsigned)__popcll(bal);
    unsigned basep = 0u;
    if (lane == 0) basep = atomicAdd(&wsu[0], wcnt);
    basep = __shfl(basep, 0, 64);
    if (m) {
      unsigned pos = basep + (unsigned)__popcll(bal & ((1ull << lane) - 1ull));
      if (pos < 2048u) wsu[4 + pos] = ((unsigned)c << 8) | m;
    }
  }
}

// ---------------------------------------------------------------------------
// ASYNC-STAGED ROW + R9 SELECTION. R8/R9 proved hipcc sinks every global
// load to its use (VGPR 24-28, no spill), collapsing all source pipelines
// into serialized load->wait->compute rounds (~10 x 1100cy per wave = the
// stubborn ~60us). Fix: stage the whole row into LDS with 10 back-to-back
// global_load_lds calls (un-sinkable), pay HBM latency ONCE per block at the
// __syncthreads vmcnt(0) drain, overlap across 4 resident blocks/CU, and run
// the proven per-lane-top-11 + ballot binary search out of LDS.
// ---------------------------------------------------------------------------

#define FOR11(OP) OP(0) OP(1) OP(2) OP(3) OP(4) OP(5) OP(6) OP(7) OP(8) OP(9) OP(10)
#define FOR11I(OP) OP(0) OP(1) OP(2) OP(3) OP(4) OP(5) OP(6) OP(7) OP(8) OP(9) OP(10)
#define FOR8(OP) OP(0) OP(1) OP(2) OP(3) OP(4) OP(5) OP(6) OP(7)

#define DECL_S(k) float s_##k = NINF;
#define INS1(k) { float _hi = fmaxf(s_##k, cv); cv = fminf(s_##k, cv); s_##k = _hi; }
#define TOP11V(v) { float cv = (v); FOR11I(INS1) }
#define TOP4(T) { TOP11V((T).x) TOP11V((T).y) TOP11V((T).z) TOP11V((T).w) }

__global__ __launch_bounds__(256) void loss_kernel(
    const float* __restrict__ x, const float* __restrict__ y,
    const unsigned* __restrict__ wsu, float* __restrict__ partials) {
  __shared__ float4 sh_row[2404];      // 38.46 KB; reused for top-11 publish
  __shared__ float sh_wlm[4][8];       // per-wave reduced whitelist maxes
  __shared__ unsigned sh_wpm[4];       // per-wave reduced pmask

  const int tid = threadIdx.x;
  const int lane = tid & 63;
  const int w = tid >> 6;              // 0..3
  const int r = blockIdx.x;            // one row per block
  const long long base = (long long)r * CC;

  const unsigned nu = min(wsu[0], 2048u);
  const unsigned* ents = wsu + 4;

  // Aligned float4 region [soff, soff+4*ng); ng in {2400,2401}; head+tail
  // scalars m_extra <= 5.
  const int soff = (4 - (r & 3)) & 3;
  const int ng = (CC - soff) >> 2;
  const int tailn = CC - soff - (ng << 2);
  const int m_extra = soff + tailn;
  const float4* vp = (const float4*)(x + base + soff);

  // ---- 1. stage the row: 10 async calls, ALL in flight at once ----
  // Call k moves group tid+256k; lane-order == linear dest (required layout).
#pragma unroll
  for (int k = 0; k < 9; ++k) {        // max idx 255+2048=2303 < 2400 <= ng
    stage16(vp + tid + 256 * k, &sh_row[tid + 256 * k]);
  }
  if (tid + 2304 < ng) {               // 96 or 97 threads
    stage16(vp + tid + 2304, &sh_row[tid + 2304]);
  }

  // ---- 2. whitelist gathers + scalar head/tail as normal loads (complete
  //         under the same drain) ----
  unsigned en0 = ((unsigned)tid < nu) ? ents[tid] : 0u;
  unsigned en1 = ((unsigned)tid + 256u < nu) ? ents[tid + 256] : 0u;
  float gx0 = x[base + (en0 >> 8)], gy0 = y[base + (en0 >> 8)];
  float gx1 = x[base + (en1 >> 8)], gy1 = y[base + (en1 >> 8)];
  float tv = NINF;                     // scalars handled by wave 3 below
  if (w == 3 && lane < m_extra) {
    int tc = (lane < soff) ? lane : (soff + (ng << 2) + (lane - soff));
    tv = x[base + tc];
  }

  __syncthreads();  // s_waitcnt vmcnt(0) lgkmcnt(0) + barrier: row in LDS

  // ---- 3. per-lane sorted top-11 over this wave's 600 groups (from LDS) --
  FOR11(DECL_S)
  const int g0 = 600 * w + lane;
#pragma unroll
  for (int k = 0; k < 9; ++k) {        // 600w + lane + 64k <= 600w+575
    float4 t = sh_row[g0 + 64 * k];
    TOP4(t)
  }
  {                                     // groups 600w+576 .. 600w+599
    float4 t = make_float4(NINF, NINF, NINF, NINF);
    if (lane < 24) t = sh_row[600 * w + 576 + lane];
    TOP4(t)
  }
  if (w == 3) {
    {                                   // group 2400 iff ng == 2401
      float4 t = make_float4(NINF, NINF, NINF, NINF);
      if (2400 + lane < ng) t = sh_row[2400 + lane];
      TOP4(t)
    }
    TOP11V(tv)                          // scalar head + tail (<= 5 values)
  }

  // ---- 4. whitelist fold + wave reduce ----
#define DECL_LM(k) float lm_##k = NEGF;
  FOR8(DECL_LM)
  unsigned pmask = 0u;  // bits0-7: label present; bits8-15: label has positive
#define FOLDE(EN, GX, GY)                                        \
  {                                                              \
    unsigned mk = (EN) & 255u; /* 0 for empty slot -> no-op */   \
    pmask |= mk;                                                 \
    if ((GY) > 0.0f) pmask |= (mk << 8);                         \
    if (mk & 1u)   lm_0 = fmaxf(lm_0, (GX));                     \
    if (mk & 2u)   lm_1 = fmaxf(lm_1, (GX));                     \
    if (mk & 4u)   lm_2 = fmaxf(lm_2, (GX));                     \
    if (mk & 8u)   lm_3 = fmaxf(lm_3, (GX));                     \
    if (mk & 16u)  lm_4 = fmaxf(lm_4, (GX));                     \
    if (mk & 32u)  lm_5 = fmaxf(lm_5, (GX));                     \
    if (mk & 64u)  lm_6 = fmaxf(lm_6, (GX));                     \
    if (mk & 128u) lm_7 = fmaxf(lm_7, (GX));                     \
  }
  FOLDE(en0, gx0, gy0)
  FOLDE(en1, gx1, gy1)
  // safety net (nu <= ~400 here; loop normally never runs)
  for (unsigned e = 512u + (unsigned)tid; e < nu; e += 256u) {
    unsigned ent = ents[e];
    float xv = x[base + (ent >> 8)];
    float yv = y[base + (ent >> 8)];
    FOLDE(ent, xv, yv)
  }
#pragma unroll
  for (int off = 32; off >= 1; off >>= 1) {
    pmask |= __shfl_xor(pmask, off, 64);
#define RED1(l) lm_##l = fmaxf(lm_##l, __shfl_xor(lm_##l, off, 64));
    FOR8(RED1)
#undef RED1
  }

  // ---- 5. publish into the (consumed) row LDS; two cheap barriers ----
  float* shf = (float*)sh_row;
  __syncthreads();                     // all LDS row reads complete
  if (w > 0) {
#define ST1(k) shf[((w - 1) * 64 + lane) * 11 + k] = s_##k;
    FOR11(ST1)
#undef ST1
  }
  if (lane == 0) {
#define STL(l) sh_wlm[w][l] = lm_##l;
    FOR8(STL)
#undef STL
    sh_wpm[w] = pmask;
  }
  __syncthreads();
  if (w != 0) return;

  // merge waves 1-3 per-lane lists (33 inserts; stride 11 words -> lanes
  // spread over all 32 banks, 2/bank = conflict-free)
#pragma unroll
  for (int j = 0; j < 3; ++j) {
#pragma unroll
    for (int k = 0; k < 11; ++k) {
      TOP11V(shf[(j * 64 + lane) * 11 + k])
    }
  }

  // ---- 6. exact 11th-largest via value binary search (ballots only) ----
  // Exactness: any dropped value < its lane's stream-11th <= that lane's
  // merged-11th <= lo = wave-max(merged 11th), so candidate counts are
  // exact for T > lo.
#define DECL_E(k) unsigned e_##k = enc_f(s_##k);
  FOR11(DECL_E)
#undef DECL_E
  unsigned wlo = e_10;
  unsigned whi = e_0;
#pragma unroll
  for (int off = 32; off >= 1; off >>= 1) {
    wlo = max(wlo, __shfl_xor(wlo, off, 64));
    whi = max(whi, __shfl_xor(whi, off, 64));
  }
  unsigned lo = wlo, hi = whi + 1u;
  while (hi - lo > 1u) {               // uniform; <= ~25 iters
    unsigned mid = lo + ((hi - lo) >> 1);
    unsigned cnt = 0u;
#define CMP1(k) cnt += (e_##k >= mid) ? 1u : 0u;
    FOR11(CMP1)
#undef CMP1
    unsigned tot = (unsigned)__popcll(__ballot(cnt & 1u)) +
                   ((unsigned)__popcll(__ballot(cnt & 2u)) << 1) +
                   ((unsigned)__popcll(__ballot(cnt & 4u)) << 2) +
                   ((unsigned)__popcll(__ballot(cnt & 8u)) << 3);
    if (tot >= 11u) lo = mid; else hi = mid;
  }
  const unsigned E11 = lo;  // exact 11th-largest (encoded)

  // ---- 7. lane 0: combine per-wave whitelist partials, per-row loss ----
  if (lane == 0) {
#pragma unroll
    for (int j = 1; j < 4; ++j) {
      pmask |= sh_wpm[j];
#define CMB(l) lm_##l = fmaxf(lm_##l, sh_wlm[j][l]);
      FOR8(CMB)
#undef CMB
    }
    unsigned PR = pmask & 255u, PO = (pmask >> 8) & 255u;
    float thres = fmaxf(sigm(dec_u(E11)), 0.5f);
    float cmax = NEGF, imax = NEGF, umax = NEGF;
#define EP1(l)                                                   \
    if ((PR >> l) & 1u) {                                        \
      float ml = sigm(lm_##l);                                   \
      umax = fmaxf(umax, ml);                                    \
      if ((PO >> l) & 1u) cmax = fmaxf(cmax, ml);                \
      else imax = fmaxf(imax, ml);                               \
    }
    FOR8(EP1)
#undef EP1
    bool anyc = (PO != 0u);
    bool anyi = (PO != 255u);  // L == 8 labels always exist
    float x1 = anyc ? cmax : thres;
    float x2 = anyc ? (anyi ? fmaxf(imax, thres) : thres)
                    : ((nu > 0u) ? umax : NEGF);
    float coef = anyc ? 1.0f : 0.5f;
    float dd = x2 - x1 + 0.1f;
    float rank = ((dd > 0.0f) ? 2.0f : 1.0f) * sigm(10.0f * dd);
    partials[r] = coef * rank;
  }
}

__global__ void final_reduce(const float* __restrict__ partials,
                             float* __restrict__ out) {
  __shared__ float sh[4];
  const int tid = threadIdx.x;
  const int lane = tid & 63;
  const int wid = tid >> 6;
  float s = 0.0f;
  for (int i = tid; i < BB; i += 256) s += partials[i];
#pragma unroll
  for (int off = 32; off >= 1; off >>= 1) s += __shfl_xor(s, off, 64);
  if (lane == 0) sh[wid] = s;
  __syncthreads();
  if (tid == 0) out[0] = (sh[0] + sh[1] + sh[2] + sh[3]) * (1.0f / (float)BB);
}

extern "C" void kernel_launch(void* const* d_in, const int* in_sizes, int n_in,
                              void* d_out, int out_size, void* d_ws,
                              size_t ws_size, hipStream_t stream) {
  const float* x = (const float*)d_in[0];
  const float* y = (const float*)d_in[1];
  // d_in[2] (y_neg) is faithfully ignored — it never affects the loss.
  const unsigned char* wl = (const unsigned char*)d_in[3];
  float* out = (float*)d_out;
  unsigned* wsu = (unsigned*)d_ws;
  float* partials = (float*)((char*)d_ws + WS_PARTIALS_OFF);

  hipMemsetAsync(d_ws, 0, 16, stream);  // zero wsu[0..3]
  wl_sniff<<<64, 256, 0, stream>>>((const unsigned*)wl, wsu);
  wl_compact<<<(CC + 255) / 256, 256, 0, stream>>>(wl, wsu);
  loss_kernel<<<BB, 256, 0, stream>>>(x, y, wsu, partials);
  final_reduce<<<1, 256, 0, stream>>>(partials, out);
}